// Round 5
// baseline (1099.805 us; speedup 1.0000x reference)
//
#include <hip/hip_runtime.h>

// Problem constants
#define ND 128      // model dim D
#define NH 8        // heads
#define DHD 16      // head dim

// ---------------------------------------------------------------------------
// Tiny kernel: per-head column sums of W_pd / W_pm and bias sums.
// wpd/wpm layout: [k][h] -> k*8+h
// ---------------------------------------------------------------------------
__global__ void k_wsum(const float* __restrict__ Wpd, const float* __restrict__ bpd,
                       const float* __restrict__ Wpm, const float* __restrict__ bpm,
                       float* __restrict__ wpd, float* __restrict__ wpm,
                       float* __restrict__ bs) {
  int t = blockIdx.x * blockDim.x + threadIdx.x;
  if (t < 1024) {
    int k = t >> 3, h = t & 7;
    float s = 0.f;
#pragma unroll
    for (int d = 0; d < 16; ++d) s += Wpd[k * 128 + h * 16 + d];
    wpd[t] = s;
  } else if (t < 2048) {
    int u = t - 1024, k = u >> 3, h = u & 7;
    float s = 0.f;
#pragma unroll
    for (int d = 0; d < 16; ++d) s += Wpm[k * 128 + h * 16 + d];
    wpm[u] = s;
  } else if (t < 2056) {
    int h = t - 2048;
    float s = 0.f;
#pragma unroll
    for (int d = 0; d < 16; ++d) s += bpd[h * 16 + d] + bpm[h * 16 + d];
    bs[h] = s;
  }
}

// ---------------------------------------------------------------------------
// QKV projection, 3-group layout: 384 threads; group g (0..2) computes
// Q/K/V respectively with the proven 8-acc gemm_bias register shape.
// X staged once and shared.
// ---------------------------------------------------------------------------
__global__ __launch_bounds__(384) void k_qkv3(const float* __restrict__ X,
                                              const float* __restrict__ WQ, const float* __restrict__ bQ,
                                              const float* __restrict__ WK, const float* __restrict__ bK,
                                              const float* __restrict__ WV, const float* __restrict__ bV,
                                              float* __restrict__ Q, float* __restrict__ Ko,
                                              float* __restrict__ V, int n) {
  __shared__ float xs[8][128];
  const int t = threadIdx.x;
  const int c = t & 127;
  const int grp = t >> 7;  // 0=Q, 1=K, 2=V
  const int r0 = blockIdx.x * 8;
  const int nr = min(8, n - r0);
  for (int i = t; i < nr * 32; i += 384)
    ((float4*)xs)[i] = ((const float4*)(X + (size_t)r0 * 128))[i];
  __syncthreads();
  const float* __restrict__ W = (grp == 0) ? WQ : (grp == 1) ? WK : WV;
  const float* __restrict__ B = (grp == 0) ? bQ : (grp == 1) ? bK : bV;
  float* __restrict__ Y = (grp == 0) ? Q : (grp == 1) ? Ko : V;
  float acc[8];
#pragma unroll
  for (int r = 0; r < 8; ++r) acc[r] = 0.f;
  for (int k = 0; k < 128; ++k) {
    const float w = W[k * 128 + c];
#pragma unroll
    for (int r = 0; r < 8; ++r) acc[r] += xs[r][k] * w;
  }
  const float b = B[c];
  for (int r = 0; r < nr; ++r)
    Y[(size_t)(r0 + r) * 128 + c] = acc[r] + b;
}

// ---------------------------------------------------------------------------
// Edge bias-score kernel v3: thread-per-2-edges, no data staging.
// Weights (8 KB) in LDS, read at wave-uniform addresses (broadcast).
// de/m rows streamed directly as float4; 16 head-accs in registers.
// ---------------------------------------------------------------------------
__device__ __forceinline__ void acc8(float d, float g,
                                     const float* __restrict__ wdk,
                                     const float* __restrict__ wmk,
                                     float4& a0, float4& a1) {
  const float4 wd0 = *(const float4*)wdk;
  const float4 wd1 = *(const float4*)(wdk + 4);
  const float4 wm0 = *(const float4*)wmk;
  const float4 wm1 = *(const float4*)(wmk + 4);
  a0.x += d * wd0.x + g * wm0.x; a0.y += d * wd0.y + g * wm0.y;
  a0.z += d * wd0.z + g * wm0.z; a0.w += d * wd0.w + g * wm0.w;
  a1.x += d * wd1.x + g * wm1.x; a1.y += d * wd1.y + g * wm1.y;
  a1.z += d * wd1.z + g * wm1.z; a1.w += d * wd1.w + g * wm1.w;
}

__global__ __launch_bounds__(256) void k_esum3(const float* __restrict__ de,
                                               const float* __restrict__ m,
                                               const float* __restrict__ wpd,
                                               const float* __restrict__ wpm,
                                               const float* __restrict__ bs,
                                               float* __restrict__ esum, int E_) {
  __shared__ float swd[1024];
  __shared__ float swm[1024];
  __shared__ float sbs[8];
  const int t = threadIdx.x;
  for (int i = t; i < 1024; i += 256) { swd[i] = wpd[i]; swm[i] = wpm[i]; }
  if (t < 8) sbs[t] = bs[t];
  __syncthreads();
  const int e0 = blockIdx.x * 512 + t;
  const int e1 = e0 + 256;
  const bool v0 = e0 < E_, v1 = e1 < E_;
  const float* __restrict__ p0 = de + (size_t)e0 * 128;
  const float* __restrict__ q0 = m + (size_t)e0 * 128;
  const float* __restrict__ p1 = de + (size_t)e1 * 128;
  const float* __restrict__ q1 = m + (size_t)e1 * 128;
  float4 A00 = make_float4(0.f, 0.f, 0.f, 0.f), A01 = A00;
  float4 A10 = A00, A11 = A00;
#pragma unroll 4
  for (int kb = 0; kb < 32; ++kb) {
    float4 d0 = make_float4(0.f, 0.f, 0.f, 0.f), g0 = d0, d1 = d0, g1 = d0;
    if (v0) { d0 = *(const float4*)(p0 + kb * 4); g0 = *(const float4*)(q0 + kb * 4); }
    if (v1) { d1 = *(const float4*)(p1 + kb * 4); g1 = *(const float4*)(q1 + kb * 4); }
    const float* wd = &swd[kb * 32];
    const float* wm = &swm[kb * 32];
    acc8(d0.x, g0.x, wd, wm, A00, A01);
    acc8(d0.y, g0.y, wd + 8, wm + 8, A00, A01);
    acc8(d0.z, g0.z, wd + 16, wm + 16, A00, A01);
    acc8(d0.w, g0.w, wd + 24, wm + 24, A00, A01);
    acc8(d1.x, g1.x, wd, wm, A10, A11);
    acc8(d1.y, g1.y, wd + 8, wm + 8, A10, A11);
    acc8(d1.z, g1.z, wd + 16, wm + 16, A10, A11);
    acc8(d1.w, g1.w, wd + 24, wm + 24, A10, A11);
  }
  const float4 sb0 = *(const float4*)&sbs[0];
  const float4 sb1 = *(const float4*)&sbs[4];
  if (v0) {
    A00.x += sb0.x; A00.y += sb0.y; A00.z += sb0.z; A00.w += sb0.w;
    A01.x += sb1.x; A01.y += sb1.y; A01.z += sb1.z; A01.w += sb1.w;
    *(float4*)(esum + (size_t)e0 * 8) = A00;
    *(float4*)(esum + (size_t)e0 * 8 + 4) = A01;
  }
  if (v1) {
    A10.x += sb0.x; A10.y += sb0.y; A10.z += sb0.z; A10.w += sb0.w;
    A11.x += sb1.x; A11.y += sb1.y; A11.z += sb1.z; A11.w += sb1.w;
    *(float4*)(esum + (size_t)e1 * 8) = A10;
    *(float4*)(esum + (size_t)e1 * 8 + 4) = A11;
  }
}

// ---------------------------------------------------------------------------
// CSR build: histogram, scan, scatter
// ---------------------------------------------------------------------------
__global__ __launch_bounds__(256) void k_hist(const int* __restrict__ dst,
                                              int* __restrict__ counts, int E_) {
  const int i = blockIdx.x * blockDim.x + threadIdx.x;
  const int n = gridDim.x * blockDim.x;
  for (int e = i; e < E_; e += n) atomicAdd(&counts[dst[e]], 1);
}

__global__ __launch_bounds__(1024) void k_scan(const int* __restrict__ counts,
                                               int* __restrict__ rs,
                                               int* __restrict__ cursor, int N_) {
  __shared__ int ls[1024];
  const int t = threadIdx.x;
  const int CH = (N_ + 1023) >> 10;
  const int b0 = t * CH, b1 = min(N_, b0 + CH);
  int s = 0;
  for (int i = b0; i < b1; ++i) s += counts[i];
  ls[t] = s;
  __syncthreads();
  for (int off = 1; off < 1024; off <<= 1) {
    int v = (t >= off) ? ls[t - off] : 0;
    __syncthreads();
    ls[t] += v;
    __syncthreads();
  }
  int run = ls[t] - s;
  for (int i = b0; i < b1; ++i) {
    rs[i] = run;
    cursor[i] = run;
    run += counts[i];
  }
  if (t == 1023) rs[N_] = ls[1023];
}

__global__ __launch_bounds__(256) void k_scatter(const int* __restrict__ src,
                                                 const int* __restrict__ dst,
                                                 int* __restrict__ cursor,
                                                 int2* __restrict__ eidx, int E_) {
  const int i = blockIdx.x * blockDim.x + threadIdx.x;
  const int n = gridDim.x * blockDim.x;
  for (int e = i; e < E_; e += n) {
    int d = dst[e];
    int p = atomicAdd(&cursor[d], 1);
    eidx[p] = make_int2(src[e], e);
  }
}

// ---------------------------------------------------------------------------
// Gather-side attention: one wave per dst node, head-per-lane layout.
// lane = (g,l): g = edge slot (0..7), l = head (0..7).
// ---------------------------------------------------------------------------
__global__ __launch_bounds__(256) void k_node_attn(const float* __restrict__ Q,
                                                   const float* __restrict__ K,
                                                   const float* __restrict__ V,
                                                   const float* __restrict__ esum,
                                                   const int* __restrict__ rs,
                                                   const int2* __restrict__ eidx,
                                                   float* __restrict__ wV,
                                                   float* __restrict__ z, int n) {
  const int node = (blockIdx.x * blockDim.x + threadIdx.x) >> 6;
  if (node >= n) return;
  const int lane = threadIdx.x & 63;
  const int g = lane >> 3;   // edge slot
  const int l = lane & 7;    // head
  const int d0 = l << 4;     // this head's dim base
  const float* qp = Q + (size_t)node * 128 + d0;
  const float4 q0 = *(const float4*)(qp);
  const float4 q1 = *(const float4*)(qp + 4);
  const float4 q2 = *(const float4*)(qp + 8);
  const float4 q3 = *(const float4*)(qp + 12);
  float4 a0 = make_float4(0.f, 0.f, 0.f, 0.f);
  float4 a1 = a0, a2 = a0, a3 = a0;
  float zacc = 0.f;
  const int start = rs[node], end = rs[node + 1];
  for (int base = start; base < end; base += 8) {
    const int idx = base + g;
    if (idx < end) {
      const int2 me = eidx[idx];
      const float* kp = K + (size_t)me.x * 128 + d0;
      const float4 k0 = *(const float4*)(kp);
      const float4 k1 = *(const float4*)(kp + 4);
      const float4 k2 = *(const float4*)(kp + 8);
      const float4 k3 = *(const float4*)(kp + 12);
      const float es = esum[(size_t)me.y * 8 + l];
      float qk = q0.x * k0.x + q0.y * k0.y + q0.z * k0.z + q0.w * k0.w
               + q1.x * k1.x + q1.y * k1.y + q1.z * k1.z + q1.w * k1.w
               + q2.x * k2.x + q2.y * k2.y + q2.z * k2.z + q2.w * k2.w
               + q3.x * k3.x + q3.y * k3.y + q3.z * k3.z + q3.w * k3.w;
      float sc = 4.f * qk + es;
      sc = fminf(5.f, fmaxf(-5.f, sc));
      const float s = __expf(sc);
      const float* vp = V + (size_t)me.x * 128 + d0;
      const float4 v0 = *(const float4*)(vp);
      const float4 v1 = *(const float4*)(vp + 4);
      const float4 v2 = *(const float4*)(vp + 8);
      const float4 v3 = *(const float4*)(vp + 12);
      a0.x += v0.x * s; a0.y += v0.y * s; a0.z += v0.z * s; a0.w += v0.w * s;
      a1.x += v1.x * s; a1.y += v1.y * s; a1.z += v1.z * s; a1.w += v1.w * s;
      a2.x += v2.x * s; a2.y += v2.y * s; a2.z += v2.z * s; a2.w += v2.w * s;
      a3.x += v3.x * s; a3.y += v3.y * s; a3.z += v3.z * s; a3.w += v3.w * s;
      zacc += s;
    }
  }
#pragma unroll
  for (int st = 8; st < 64; st <<= 1) {
    a0.x += __shfl_xor(a0.x, st); a0.y += __shfl_xor(a0.y, st);
    a0.z += __shfl_xor(a0.z, st); a0.w += __shfl_xor(a0.w, st);
    a1.x += __shfl_xor(a1.x, st); a1.y += __shfl_xor(a1.y, st);
    a1.z += __shfl_xor(a1.z, st); a1.w += __shfl_xor(a1.w, st);
    a2.x += __shfl_xor(a2.x, st); a2.y += __shfl_xor(a2.y, st);
    a2.z += __shfl_xor(a2.z, st); a2.w += __shfl_xor(a2.w, st);
    a3.x += __shfl_xor(a3.x, st); a3.y += __shfl_xor(a3.y, st);
    a3.z += __shfl_xor(a3.z, st); a3.w += __shfl_xor(a3.w, st);
    zacc += __shfl_xor(zacc, st);
  }
  if (g < 4) {
    float4 w = a0;
    if (g == 1) w = a1;
    if (g == 2) w = a2;
    if (g == 3) w = a3;
    *(float4*)(wV + (size_t)node * 128 + d0 + (g << 2)) = w;
  }
  if (g == 0) z[(size_t)node * 8 + l] = zacc;
}

// ---------------------------------------------------------------------------
// attn normalize + I @ W_i + b_i  -> T[n,128]
// ---------------------------------------------------------------------------
__global__ __launch_bounds__(128) void k_attn_combine(const float* __restrict__ I_,
                                                      const float* __restrict__ Wi,
                                                      const float* __restrict__ bi,
                                                      const float* __restrict__ wV,
                                                      const float* __restrict__ z,
                                                      float* __restrict__ T, int n) {
  __shared__ float xs[8][64];
  const int c = threadIdx.x;
  const int r0 = blockIdx.x * 8;
  const int nr = min(8, n - r0);
  for (int i = c; i < nr * 64; i += 128) xs[i >> 6][i & 63] = I_[r0 * 64 + i];
  __syncthreads();
  float acc[8];
#pragma unroll
  for (int r = 0; r < 8; ++r) acc[r] = 0.f;
  for (int k = 0; k < 64; ++k) {
    float w = Wi[k * 128 + c];
#pragma unroll
    for (int r = 0; r < 8; ++r) acc[r] += xs[r][k] * w;
  }
  const float b = bi[c];
  const int hh = c >> 4;
  for (int r = 0; r < nr; ++r) {
    const size_t row = r0 + r;
    const float attn = wV[row * 128 + c] / (z[row * 8 + hh] + 1e-10f);
    T[row * 128 + c] = attn + acc[r] + b;
  }
}

// ---------------------------------------------------------------------------
// 4x4 register-tiled GEMM + bias (+ReLU): 64x64 tile, 256 threads (16x16).
// ---------------------------------------------------------------------------
template <int CI, int CO, bool RELU>
__global__ __launch_bounds__(256) void k_gemm4(const float* __restrict__ X,
                                               const float* __restrict__ W,
                                               const float* __restrict__ B,
                                               float* __restrict__ Y, int n) {
  __shared__ float xs[64][CI + 4];
  const int t = threadIdx.x;
  const int tx = t & 15, ty = t >> 4;
  const int r0 = blockIdx.x * 64;
  const int c0 = blockIdx.y * 64;
  const int NV = 64 * (CI / 4);
  for (int i = t; i < NV; i += 256) {
    const int row = i / (CI / 4);
    const int c4 = (i % (CI / 4)) << 2;
    float4 v = make_float4(0.f, 0.f, 0.f, 0.f);
    if (r0 + row < n) v = *(const float4*)(X + (size_t)(r0 + row) * CI + c4);
    *(float4*)&xs[row][c4] = v;
  }
  __syncthreads();
  float4 acc[4];
#pragma unroll
  for (int i = 0; i < 4; ++i) acc[i] = make_float4(0.f, 0.f, 0.f, 0.f);
  const int ty4 = ty << 2;
#pragma unroll 4
  for (int k = 0; k < CI; ++k) {
    const float4 wv = *(const float4*)(W + (size_t)k * CO + c0 + (tx << 2));
    const float x0 = xs[ty4 + 0][k];
    const float x1 = xs[ty4 + 1][k];
    const float x2 = xs[ty4 + 2][k];
    const float x3 = xs[ty4 + 3][k];
    acc[0].x += x0 * wv.x; acc[0].y += x0 * wv.y; acc[0].z += x0 * wv.z; acc[0].w += x0 * wv.w;
    acc[1].x += x1 * wv.x; acc[1].y += x1 * wv.y; acc[1].z += x1 * wv.z; acc[1].w += x1 * wv.w;
    acc[2].x += x2 * wv.x; acc[2].y += x2 * wv.y; acc[2].z += x2 * wv.z; acc[2].w += x2 * wv.w;
    acc[3].x += x3 * wv.x; acc[3].y += x3 * wv.y; acc[3].z += x3 * wv.z; acc[3].w += x3 * wv.w;
  }
  const float4 bv = *(const float4*)(B + c0 + (tx << 2));
#pragma unroll
  for (int i = 0; i < 4; ++i) {
    const int row = r0 + ty4 + i;
    if (row < n) {
      float4 o;
      o.x = acc[i].x + bv.x; o.y = acc[i].y + bv.y;
      o.z = acc[i].z + bv.z; o.w = acc[i].w + bv.w;
      if (RELU) {
        o.x = fmaxf(o.x, 0.f); o.y = fmaxf(o.y, 0.f);
        o.z = fmaxf(o.z, 0.f); o.w = fmaxf(o.w, 0.f);
      }
      *(float4*)(Y + (size_t)row * CO + c0 + (tx << 2)) = o;
    }
  }
}

// ---------------------------------------------------------------------------
// GEMM (CI->128) + bias + residual + LayerNorm + eval-BatchNorm, fused.
// ---------------------------------------------------------------------------
template <int CI>
__global__ __launch_bounds__(128) void k_gemm_ln(const float* __restrict__ X,
                                                 const float* __restrict__ W,
                                                 const float* __restrict__ B,
                                                 const float* __restrict__ RES,
                                                 const float* __restrict__ lng,
                                                 const float* __restrict__ lnb,
                                                 const float* __restrict__ bng,
                                                 const float* __restrict__ bnb,
                                                 float* __restrict__ Y, int n) {
  __shared__ float xs[8][CI];
  __shared__ float ys[8][128];
  __shared__ float mu_s[8], rs_s[8];
  const int c = threadIdx.x;
  const int r0 = blockIdx.x * 8;
  const int nr = min(8, n - r0);
  for (int i = c; i < nr * CI; i += 128) xs[i / CI][i % CI] = X[(size_t)r0 * CI + i];
  __syncthreads();
  float acc[8];
#pragma unroll
  for (int r = 0; r < 8; ++r) acc[r] = 0.f;
  for (int k = 0; k < CI; ++k) {
    float w = W[k * 128 + c];
#pragma unroll
    for (int r = 0; r < 8; ++r) acc[r] += xs[r][k] * w;
  }
  const float b = B[c];
  for (int r = 0; r < nr; ++r)
    ys[r][c] = acc[r] + b + RES[(size_t)(r0 + r) * 128 + c];
  __syncthreads();
  const int gr = c >> 4, j = c & 15;
  float s1 = 0.f, s2 = 0.f;
#pragma unroll
  for (int i = 0; i < 8; ++i) {
    float v = ys[gr][j + 16 * i];
    s1 += v;
    s2 += v * v;
  }
#pragma unroll
  for (int st = 1; st < 16; st <<= 1) {
    s1 += __shfl_xor(s1, st);
    s2 += __shfl_xor(s2, st);
  }
  if (j == 0) {
    const float mu = s1 * (1.f / 128.f);
    const float var = s2 * (1.f / 128.f) - mu * mu;
    mu_s[gr] = mu;
    rs_s[gr] = rsqrtf(var + 1e-5f);
  }
  __syncthreads();
  const float bnscale = rsqrtf(1.f + 1e-5f);
  const float g_c = lng[c], lb_c = lnb[c], bg_c = bng[c] * bnscale, bb_c = bnb[c];
  for (int r = 0; r < nr; ++r) {
    const float v = ys[r][c];
    const float t = (v - mu_s[r]) * rs_s[r] * g_c + lb_c;
    Y[(size_t)(r0 + r) * 128 + c] = t * bg_c + bb_c;
  }
}

// ---------------------------------------------------------------------------
extern "C" void kernel_launch(void* const* d_in, const int* in_sizes, int n_in,
                              void* d_out, int out_size, void* d_ws, size_t ws_size,
                              hipStream_t stream) {
  const float* h_   = (const float*)d_in[0];
  const float* de   = (const float*)d_in[1];
  const float* m_   = (const float*)d_in[2];
  const float* I_   = (const float*)d_in[3];
  const float* W_Q  = (const float*)d_in[4];
  const float* b_Q  = (const float*)d_in[5];
  const float* W_K  = (const float*)d_in[6];
  const float* b_K  = (const float*)d_in[7];
  const float* W_V  = (const float*)d_in[8];
  const float* b_V  = (const float*)d_in[9];
  const float* W_pd = (const float*)d_in[10];
  const float* b_pd = (const float*)d_in[11];
  const float* W_pm = (const float*)d_in[12];
  const float* b_pm = (const float*)d_in[13];
  const float* W_i  = (const float*)d_in[14];
  const float* b_i  = (const float*)d_in[15];
  const float* W_O  = (const float*)d_in[16];
  const float* b_O  = (const float*)d_in[17];
  const float* ln1g = (const float*)d_in[18];
  const float* ln1b = (const float*)d_in[19];
  const float* bn1g = (const float*)d_in[20];
  const float* bn1b = (const float*)d_in[21];
  const float* W_f1 = (const float*)d_in[22];
  const float* b_f1 = (const float*)d_in[23];
  const float* W_f2 = (const float*)d_in[24];
  const float* b_f2 = (const float*)d_in[25];
  const float* ln2g = (const float*)d_in[26];
  const float* ln2b = (const float*)d_in[27];
  const float* bn2g = (const float*)d_in[28];
  const float* bn2b = (const float*)d_in[29];
  const int* src    = (const int*)d_in[30];
  const int* dst    = (const int*)d_in[31];

  const int N_ = in_sizes[0] / 128;   // 50000
  const int E_ = in_sizes[30];        // 800000
  const size_t ND_ = (size_t)N_ * 128;

  float* ws = (float*)d_ws;
  size_t off = 0;
  float* Qb   = ws + off; off += ND_;
  float* Kb   = ws + off; off += ND_;
  float* Vb   = ws + off; off += ND_;
  float* wV   = ws + off; off += ND_;
  float* zb   = ws + off; off += (size_t)N_ * 8;
  float* esum = ws + off; off += (size_t)E_ * 8;
  float* Tb   = ws + off; off += ND_;
  float* h2   = ws + off; off += ND_;
  float* hid  = ws + off; off += (size_t)N_ * 256;   // FFN scratch; CSR aliased here
  float* wpd  = ws + off; off += 1024;
  float* wpm  = ws + off; off += 1024;
  float* bs   = ws + off; off += 8;
  (void)ws_size; (void)n_in; (void)out_size;

  // CSR arrays aliased into hid (dead until FFN stage)
  int*  rs     = (int*)hid;                  // N+1 (padded to N+2)
  int*  cursor = rs + (N_ + 2);              // N (padded to N+2)
  int2* eidx   = (int2*)(cursor + (N_ + 2)); // E entries (src, eid)

  float* out = (float*)d_out;
  const int nrb = (N_ + 7) / 8;
  const int nrb64 = (N_ + 63) / 64;

  // 1. weight head-sums
  k_wsum<<<9, 256, 0, stream>>>(W_pd, b_pd, W_pm, b_pm, wpd, wpm, bs);

  // 2. Q,K,V projection (3-group, shared X stage)
  k_qkv3<<<nrb, 384, 0, stream>>>(h_, W_Q, b_Q, W_K, b_K, W_V, b_V, Qb, Kb, Vb, N_);

  // 3. edge bias scores (stream-bound on de + m; no staging)
  k_esum3<<<(E_ + 511) / 512, 256, 0, stream>>>(de, m_, wpd, wpm, bs, esum, E_);

  // 4. CSR build: counts -> scan -> scatter
  hipMemsetAsync(cursor, 0, (size_t)N_ * sizeof(int), stream);
  k_hist<<<1024, 256, 0, stream>>>(dst, cursor, E_);
  k_scan<<<1, 1024, 0, stream>>>(cursor, rs, cursor, N_);
  k_scatter<<<1024, 256, 0, stream>>>(src, dst, cursor, eidx, E_);

  // 5. gather-side attention (head-per-lane, 8 edges/wave)
  k_node_attn<<<(N_ + 3) / 4, 256, 0, stream>>>(Qb, Kb, Vb, esum, rs, eidx, wV, zb, N_);

  // 6. attn normalize + I @ W_i
  k_attn_combine<<<nrb, 128, 0, stream>>>(I_, W_i, b_i, wV, zb, Tb, N_);

  // 7. W_O + residual(h) + LN1 + BN1 -> h2
  k_gemm_ln<128><<<nrb, 128, 0, stream>>>(Tb, W_O, b_O, h_, ln1g, ln1b, bn1g, bn1b, h2, N_);

  // 8. FFN1 (ReLU), register-tiled — overwrites CSR scratch (dead by now)
  k_gemm4<128, 256, true><<<dim3(nrb64, 4), 256, 0, stream>>>(h2, W_f1, b_f1, hid, N_);

  // 9. FFN2 + residual(h2) + LN2 + BN2 -> out
  k_gemm_ln<256><<<nrb, 128, 0, stream>>>(hid, W_f2, b_f2, h2, ln2g, ln2b, bn2g, bn2b, out, N_);
}

// Round 6
// 862.055 us; speedup vs baseline: 1.2758x; 1.2758x over previous
//
#include <hip/hip_runtime.h>

// Problem constants
#define ND 128      // model dim D
#define NH 8        // heads
#define DHD 16      // head dim

// ---------------------------------------------------------------------------
// Tiny kernel: per-head column sums of W_pd / W_pm and bias sums.
// wpd/wpm layout: [k][h] -> k*8+h
// ---------------------------------------------------------------------------
__global__ void k_wsum(const float* __restrict__ Wpd, const float* __restrict__ bpd,
                       const float* __restrict__ Wpm, const float* __restrict__ bpm,
                       float* __restrict__ wpd, float* __restrict__ wpm,
                       float* __restrict__ bs) {
  int t = blockIdx.x * blockDim.x + threadIdx.x;
  if (t < 1024) {
    int k = t >> 3, h = t & 7;
    float s = 0.f;
#pragma unroll
    for (int d = 0; d < 16; ++d) s += Wpd[k * 128 + h * 16 + d];
    wpd[t] = s;
  } else if (t < 2048) {
    int u = t - 1024, k = u >> 3, h = u & 7;
    float s = 0.f;
#pragma unroll
    for (int d = 0; d < 16; ++d) s += Wpm[k * 128 + h * 16 + d];
    wpm[u] = s;
  } else if (t < 2056) {
    int h = t - 2048;
    float s = 0.f;
#pragma unroll
    for (int d = 0; d < 16; ++d) s += bpd[h * 16 + d] + bpm[h * 16 + d];
    bs[h] = s;
  }
}

// ---------------------------------------------------------------------------
// Fused QKV projection: reads h once, computes Q and interleaved KV rows.
// KV layout: [node][256] = K row (128) || V row (128) — one gather locality
// unit for node_attn.
// ---------------------------------------------------------------------------
__global__ __launch_bounds__(128) void k_qkv(const float* __restrict__ X,
                                             const float* __restrict__ WQ, const float* __restrict__ bQ,
                                             const float* __restrict__ WK, const float* __restrict__ bK,
                                             const float* __restrict__ WV, const float* __restrict__ bV,
                                             float* __restrict__ Q, float* __restrict__ KV,
                                             int n) {
  __shared__ float xs[8][128];
  const int c = threadIdx.x;
  const int r0 = blockIdx.x * 8;
  const int nr = min(8, n - r0);
  for (int i = c; i < nr * 32; i += 128)
    ((float4*)xs)[i] = ((const float4*)(X + (size_t)r0 * 128))[i];
  __syncthreads();
  float aq[8], ak[8], av[8];
#pragma unroll
  for (int r = 0; r < 8; ++r) { aq[r] = 0.f; ak[r] = 0.f; av[r] = 0.f; }
  for (int k = 0; k < 128; ++k) {
    const float wq = WQ[k * 128 + c];
    const float wk = WK[k * 128 + c];
    const float wv = WV[k * 128 + c];
#pragma unroll
    for (int r = 0; r < 8; ++r) {
      const float x = xs[r][k];
      aq[r] += x * wq;
      ak[r] += x * wk;
      av[r] += x * wv;
    }
  }
  const float q_b = bQ[c], k_b = bK[c], v_b = bV[c];
  for (int r = 0; r < nr; ++r) {
    const size_t row = r0 + r;
    Q[row * 128 + c]        = aq[r] + q_b;
    KV[row * 256 + c]       = ak[r] + k_b;
    KV[row * 256 + 128 + c] = av[r] + v_b;
  }
}

// ---------------------------------------------------------------------------
// Edge bias-score kernel: LDS-tiled skinny GEMM (proven ~140 µs, ~93% of
// the 819 MB stream floor).
// ---------------------------------------------------------------------------
__global__ __launch_bounds__(256) void k_esum2(const float* __restrict__ de,
                                               const float* __restrict__ m,
                                               const float* __restrict__ wpd,
                                               const float* __restrict__ wpm,
                                               const float* __restrict__ bs,
                                               float* __restrict__ esum, int E_) {
  __shared__ float sde[32 * 129];
  __shared__ float smm[32 * 129];
  __shared__ float swd[128 * 8];
  __shared__ float swm[128 * 8];
  __shared__ float part[8][32][8];
  const int t = threadIdx.x;
  for (int i = t; i < 1024; i += 256) { swd[i] = wpd[i]; swm[i] = wpm[i]; }
  const int e0 = blockIdx.x * 32;
  const int nr = min(32, E_ - e0);
  if (nr == 32) {
#pragma unroll
    for (int j = 0; j < 4; ++j) {
      const int f = t + j * 256;
      const int r = f >> 5, c = (f & 31) << 2;
      const float4 v = *(const float4*)(de + (size_t)(e0 + r) * 128 + c);
      const float4 w = *(const float4*)(m + (size_t)(e0 + r) * 128 + c);
      float* pd = &sde[r * 129 + c];
      pd[0] = v.x; pd[1] = v.y; pd[2] = v.z; pd[3] = v.w;
      float* pm2 = &smm[r * 129 + c];
      pm2[0] = w.x; pm2[1] = w.y; pm2[2] = w.z; pm2[3] = w.w;
    }
  } else {
#pragma unroll
    for (int j = 0; j < 4; ++j) {
      const int f = t + j * 256;
      const int r = f >> 5, c = (f & 31) << 2;
      float4 v = make_float4(0.f, 0.f, 0.f, 0.f), w = v;
      if (r < nr) {
        v = *(const float4*)(de + (size_t)(e0 + r) * 128 + c);
        w = *(const float4*)(m + (size_t)(e0 + r) * 128 + c);
      }
      float* pd = &sde[r * 129 + c];
      pd[0] = v.x; pd[1] = v.y; pd[2] = v.z; pd[3] = v.w;
      float* pm2 = &smm[r * 129 + c];
      pm2[0] = w.x; pm2[1] = w.y; pm2[2] = w.z; pm2[3] = w.w;
    }
  }
  __syncthreads();
  const int el = t & 31, kc = t >> 5;
  float acc[8];
#pragma unroll
  for (int h = 0; h < 8; ++h) acc[h] = 0.f;
  const int kbase = kc << 4;
#pragma unroll
  for (int j = 0; j < 16; ++j) {
    const int k = kbase + j;
    const float d = sde[el * 129 + k];
    const float mm = smm[el * 129 + k];
    const float4 w0 = *(const float4*)&swd[k * 8];
    const float4 w1 = *(const float4*)&swd[k * 8 + 4];
    const float4 x0 = *(const float4*)&swm[k * 8];
    const float4 x1 = *(const float4*)&swm[k * 8 + 4];
    acc[0] += d * w0.x + mm * x0.x;
    acc[1] += d * w0.y + mm * x0.y;
    acc[2] += d * w0.z + mm * x0.z;
    acc[3] += d * w0.w + mm * x0.w;
    acc[4] += d * w1.x + mm * x1.x;
    acc[5] += d * w1.y + mm * x1.y;
    acc[6] += d * w1.z + mm * x1.z;
    acc[7] += d * w1.w + mm * x1.w;
  }
  *(float4*)&part[kc][el][0] = make_float4(acc[0], acc[1], acc[2], acc[3]);
  *(float4*)&part[kc][el][4] = make_float4(acc[4], acc[5], acc[6], acc[7]);
  __syncthreads();
  const int el2 = t >> 3, h = t & 7;
  float s = bs[h];
#pragma unroll
  for (int kk = 0; kk < 8; ++kk) s += part[kk][el2][h];
  if (el2 < nr) esum[(size_t)(e0 + el2) * 8 + h] = s;
}

// ---------------------------------------------------------------------------
// CSR build: histogram, scan, scatter
// ---------------------------------------------------------------------------
__global__ __launch_bounds__(256) void k_hist(const int* __restrict__ dst,
                                              int* __restrict__ counts, int E_) {
  const int i = blockIdx.x * blockDim.x + threadIdx.x;
  const int n = gridDim.x * blockDim.x;
  for (int e = i; e < E_; e += n) atomicAdd(&counts[dst[e]], 1);
}

__global__ __launch_bounds__(1024) void k_scan(const int* __restrict__ counts,
                                               int* __restrict__ rs,
                                               int* __restrict__ cursor, int N_) {
  __shared__ int ls[1024];
  const int t = threadIdx.x;
  const int CH = (N_ + 1023) >> 10;
  const int b0 = t * CH, b1 = min(N_, b0 + CH);
  int s = 0;
  for (int i = b0; i < b1; ++i) s += counts[i];
  ls[t] = s;
  __syncthreads();
  for (int off = 1; off < 1024; off <<= 1) {
    int v = (t >= off) ? ls[t - off] : 0;
    __syncthreads();
    ls[t] += v;
    __syncthreads();
  }
  int run = ls[t] - s;
  for (int i = b0; i < b1; ++i) {
    rs[i] = run;
    cursor[i] = run;
    run += counts[i];
  }
  if (t == 1023) rs[N_] = ls[1023];
}

__global__ __launch_bounds__(256) void k_scatter(const int* __restrict__ src,
                                                 const int* __restrict__ dst,
                                                 int* __restrict__ cursor,
                                                 int2* __restrict__ eidx, int E_) {
  const int i = blockIdx.x * blockDim.x + threadIdx.x;
  const int n = gridDim.x * blockDim.x;
  for (int e = i; e < E_; e += n) {
    int d = dst[e];
    int p = atomicAdd(&cursor[d], 1);
    eidx[p] = make_int2(src[e], e);
  }
}

// ---------------------------------------------------------------------------
// Gather-side attention v3: one wave per dst node, head-per-lane layout,
// 16 edges in flight per iteration (two 8-edge slots). KV interleaved rows.
// ---------------------------------------------------------------------------
__global__ __launch_bounds__(256) void k_node_attn(const float* __restrict__ Q,
                                                   const float* __restrict__ KV,
                                                   const float* __restrict__ esum,
                                                   const int* __restrict__ rs,
                                                   const int2* __restrict__ eidx,
                                                   float* __restrict__ wV,
                                                   float* __restrict__ z, int n) {
  const int node = (blockIdx.x * blockDim.x + threadIdx.x) >> 6;
  if (node >= n) return;
  const int lane = threadIdx.x & 63;
  const int g = lane >> 3;   // edge slot
  const int l = lane & 7;    // head
  const int d0 = l << 4;     // this head's dim base
  const float* qp = Q + (size_t)node * 128 + d0;
  const float4 q0 = *(const float4*)(qp);
  const float4 q1 = *(const float4*)(qp + 4);
  const float4 q2 = *(const float4*)(qp + 8);
  const float4 q3 = *(const float4*)(qp + 12);
  float4 a0 = make_float4(0.f, 0.f, 0.f, 0.f);
  float4 a1 = a0, a2 = a0, a3 = a0;
  float zacc = 0.f;
  const int start = rs[node], end = rs[node + 1];
  for (int base = start; base < end; base += 16) {
    const int i0 = base + g;
    const int i1 = base + 8 + g;
    const bool p0 = i0 < end;
    const bool p1 = i1 < end;
    int2 m0 = make_int2(0, 0), m1 = make_int2(0, 0);
    if (p0) m0 = eidx[i0];
    if (p1) m1 = eidx[i1];
    float s0 = 0.f, s1 = 0.f;
    const float* kp0 = KV + (size_t)m0.x * 256 + d0;
    const float* kp1 = KV + (size_t)m1.x * 256 + d0;
    if (p0) {
      const float4 k0 = *(const float4*)(kp0);
      const float4 k1 = *(const float4*)(kp0 + 4);
      const float4 k2 = *(const float4*)(kp0 + 8);
      const float4 k3 = *(const float4*)(kp0 + 12);
      const float es = esum[(size_t)m0.y * 8 + l];
      float qk = q0.x * k0.x + q0.y * k0.y + q0.z * k0.z + q0.w * k0.w
               + q1.x * k1.x + q1.y * k1.y + q1.z * k1.z + q1.w * k1.w
               + q2.x * k2.x + q2.y * k2.y + q2.z * k2.z + q2.w * k2.w
               + q3.x * k3.x + q3.y * k3.y + q3.z * k3.z + q3.w * k3.w;
      float sc = fminf(5.f, fmaxf(-5.f, 4.f * qk + es));
      s0 = __expf(sc);
    }
    if (p1) {
      const float4 k0 = *(const float4*)(kp1);
      const float4 k1 = *(const float4*)(kp1 + 4);
      const float4 k2 = *(const float4*)(kp1 + 8);
      const float4 k3 = *(const float4*)(kp1 + 12);
      const float es = esum[(size_t)m1.y * 8 + l];
      float qk = q0.x * k0.x + q0.y * k0.y + q0.z * k0.z + q0.w * k0.w
               + q1.x * k1.x + q1.y * k1.y + q1.z * k1.z + q1.w * k1.w
               + q2.x * k2.x + q2.y * k2.y + q2.z * k2.z + q2.w * k2.w
               + q3.x * k3.x + q3.y * k3.y + q3.z * k3.z + q3.w * k3.w;
      float sc = fminf(5.f, fmaxf(-5.f, 4.f * qk + es));
      s1 = __expf(sc);
    }
    if (p0) {
      const float* vp = kp0 + 128;
      const float4 v0 = *(const float4*)(vp);
      const float4 v1 = *(const float4*)(vp + 4);
      const float4 v2 = *(const float4*)(vp + 8);
      const float4 v3 = *(const float4*)(vp + 12);
      a0.x += v0.x * s0; a0.y += v0.y * s0; a0.z += v0.z * s0; a0.w += v0.w * s0;
      a1.x += v1.x * s0; a1.y += v1.y * s0; a1.z += v1.z * s0; a1.w += v1.w * s0;
      a2.x += v2.x * s0; a2.y += v2.y * s0; a2.z += v2.z * s0; a2.w += v2.w * s0;
      a3.x += v3.x * s0; a3.y += v3.y * s0; a3.z += v3.z * s0; a3.w += v3.w * s0;
      zacc += s0;
    }
    if (p1) {
      const float* vp = kp1 + 128;
      const float4 v0 = *(const float4*)(vp);
      const float4 v1 = *(const float4*)(vp + 4);
      const float4 v2 = *(const float4*)(vp + 8);
      const float4 v3 = *(const float4*)(vp + 12);
      a0.x += v0.x * s1; a0.y += v0.y * s1; a0.z += v0.z * s1; a0.w += v0.w * s1;
      a1.x += v1.x * s1; a1.y += v1.y * s1; a1.z += v1.z * s1; a1.w += v1.w * s1;
      a2.x += v2.x * s1; a2.y += v2.y * s1; a2.z += v2.z * s1; a2.w += v2.w * s1;
      a3.x += v3.x * s1; a3.y += v3.y * s1; a3.z += v3.z * s1; a3.w += v3.w * s1;
      zacc += s1;
    }
  }
#pragma unroll
  for (int st = 8; st < 64; st <<= 1) {
    a0.x += __shfl_xor(a0.x, st); a0.y += __shfl_xor(a0.y, st);
    a0.z += __shfl_xor(a0.z, st); a0.w += __shfl_xor(a0.w, st);
    a1.x += __shfl_xor(a1.x, st); a1.y += __shfl_xor(a1.y, st);
    a1.z += __shfl_xor(a1.z, st); a1.w += __shfl_xor(a1.w, st);
    a2.x += __shfl_xor(a2.x, st); a2.y += __shfl_xor(a2.y, st);
    a2.z += __shfl_xor(a2.z, st); a2.w += __shfl_xor(a2.w, st);
    a3.x += __shfl_xor(a3.x, st); a3.y += __shfl_xor(a3.y, st);
    a3.z += __shfl_xor(a3.z, st); a3.w += __shfl_xor(a3.w, st);
    zacc += __shfl_xor(zacc, st);
  }
  if (g < 4) {
    float4 w = a0;
    if (g == 1) w = a1;
    if (g == 2) w = a2;
    if (g == 3) w = a3;
    *(float4*)(wV + (size_t)node * 128 + d0 + (g << 2)) = w;
  }
  if (g == 0) z[(size_t)node * 8 + l] = zacc;
}

// ---------------------------------------------------------------------------
// attn normalize + I @ W_i + b_i  -> T[n,128]
// ---------------------------------------------------------------------------
__global__ __launch_bounds__(128) void k_attn_combine(const float* __restrict__ I_,
                                                      const float* __restrict__ Wi,
                                                      const float* __restrict__ bi,
                                                      const float* __restrict__ wV,
                                                      const float* __restrict__ z,
                                                      float* __restrict__ T, int n) {
  __shared__ float xs[8][64];
  const int c = threadIdx.x;
  const int r0 = blockIdx.x * 8;
  const int nr = min(8, n - r0);
  for (int i = c; i < nr * 64; i += 128) xs[i >> 6][i & 63] = I_[r0 * 64 + i];
  __syncthreads();
  float acc[8];
#pragma unroll
  for (int r = 0; r < 8; ++r) acc[r] = 0.f;
  for (int k = 0; k < 64; ++k) {
    float w = Wi[k * 128 + c];
#pragma unroll
    for (int r = 0; r < 8; ++r) acc[r] += xs[r][k] * w;
  }
  const float b = bi[c];
  const int hh = c >> 4;
  for (int r = 0; r < nr; ++r) {
    const size_t row = r0 + r;
    const float attn = wV[row * 128 + c] / (z[row * 8 + hh] + 1e-10f);
    T[row * 128 + c] = attn + acc[r] + b;
  }
}

// ---------------------------------------------------------------------------
// 4x4 register-tiled GEMM + bias (+ReLU): 64x64 tile, 256 threads (16x16).
// ---------------------------------------------------------------------------
template <int CI, int CO, bool RELU>
__global__ __launch_bounds__(256) void k_gemm4(const float* __restrict__ X,
                                               const float* __restrict__ W,
                                               const float* __restrict__ B,
                                               float* __restrict__ Y, int n) {
  __shared__ float xs[64][CI + 4];
  const int t = threadIdx.x;
  const int tx = t & 15, ty = t >> 4;
  const int r0 = blockIdx.x * 64;
  const int c0 = blockIdx.y * 64;
  const int NV = 64 * (CI / 4);
  for (int i = t; i < NV; i += 256) {
    const int row = i / (CI / 4);
    const int c4 = (i % (CI / 4)) << 2;
    float4 v = make_float4(0.f, 0.f, 0.f, 0.f);
    if (r0 + row < n) v = *(const float4*)(X + (size_t)(r0 + row) * CI + c4);
    *(float4*)&xs[row][c4] = v;
  }
  __syncthreads();
  float4 acc[4];
#pragma unroll
  for (int i = 0; i < 4; ++i) acc[i] = make_float4(0.f, 0.f, 0.f, 0.f);
  const int ty4 = ty << 2;
#pragma unroll 4
  for (int k = 0; k < CI; ++k) {
    const float4 wv = *(const float4*)(W + (size_t)k * CO + c0 + (tx << 2));
    const float x0 = xs[ty4 + 0][k];
    const float x1 = xs[ty4 + 1][k];
    const float x2 = xs[ty4 + 2][k];
    const float x3 = xs[ty4 + 3][k];
    acc[0].x += x0 * wv.x; acc[0].y += x0 * wv.y; acc[0].z += x0 * wv.z; acc[0].w += x0 * wv.w;
    acc[1].x += x1 * wv.x; acc[1].y += x1 * wv.y; acc[1].z += x1 * wv.z; acc[1].w += x1 * wv.w;
    acc[2].x += x2 * wv.x; acc[2].y += x2 * wv.y; acc[2].z += x2 * wv.z; acc[2].w += x2 * wv.w;
    acc[3].x += x3 * wv.x; acc[3].y += x3 * wv.y; acc[3].z += x3 * wv.z; acc[3].w += x3 * wv.w;
  }
  const float4 bv = *(const float4*)(B + c0 + (tx << 2));
#pragma unroll
  for (int i = 0; i < 4; ++i) {
    const int row = r0 + ty4 + i;
    if (row < n) {
      float4 o;
      o.x = acc[i].x + bv.x; o.y = acc[i].y + bv.y;
      o.z = acc[i].z + bv.z; o.w = acc[i].w + bv.w;
      if (RELU) {
        o.x = fmaxf(o.x, 0.f); o.y = fmaxf(o.y, 0.f);
        o.z = fmaxf(o.z, 0.f); o.w = fmaxf(o.w, 0.f);
      }
      *(float4*)(Y + (size_t)row * CO + c0 + (tx << 2)) = o;
    }
  }
}

// ---------------------------------------------------------------------------
// GEMM (CI->128) + bias + residual + LayerNorm + eval-BatchNorm, fused.
// ---------------------------------------------------------------------------
template <int CI>
__global__ __launch_bounds__(128) void k_gemm_ln(const float* __restrict__ X,
                                                 const float* __restrict__ W,
                                                 const float* __restrict__ B,
                                                 const float* __restrict__ RES,
                                                 const float* __restrict__ lng,
                                                 const float* __restrict__ lnb,
                                                 const float* __restrict__ bng,
                                                 const float* __restrict__ bnb,
                                                 float* __restrict__ Y, int n) {
  __shared__ float xs[8][CI];
  __shared__ float ys[8][128];
  __shared__ float mu_s[8], rs_s[8];
  const int c = threadIdx.x;
  const int r0 = blockIdx.x * 8;
  const int nr = min(8, n - r0);
  for (int i = c; i < nr * CI; i += 128) xs[i / CI][i % CI] = X[(size_t)r0 * CI + i];
  __syncthreads();
  float acc[8];
#pragma unroll
  for (int r = 0; r < 8; ++r) acc[r] = 0.f;
  for (int k = 0; k < CI; ++k) {
    float w = W[k * 128 + c];
#pragma unroll
    for (int r = 0; r < 8; ++r) acc[r] += xs[r][k] * w;
  }
  const float b = B[c];
  for (int r = 0; r < nr; ++r)
    ys[r][c] = acc[r] + b + RES[(size_t)(r0 + r) * 128 + c];
  __syncthreads();
  const int gr = c >> 4, j = c & 15;
  float s1 = 0.f, s2 = 0.f;
#pragma unroll
  for (int i = 0; i < 8; ++i) {
    float v = ys[gr][j + 16 * i];
    s1 += v;
    s2 += v * v;
  }
#pragma unroll
  for (int st = 1; st < 16; st <<= 1) {
    s1 += __shfl_xor(s1, st);
    s2 += __shfl_xor(s2, st);
  }
  if (j == 0) {
    const float mu = s1 * (1.f / 128.f);
    const float var = s2 * (1.f / 128.f) - mu * mu;
    mu_s[gr] = mu;
    rs_s[gr] = rsqrtf(var + 1e-5f);
  }
  __syncthreads();
  const float bnscale = rsqrtf(1.f + 1e-5f);
  const float g_c = lng[c], lb_c = lnb[c], bg_c = bng[c] * bnscale, bb_c = bnb[c];
  for (int r = 0; r < nr; ++r) {
    const float v = ys[r][c];
    const float t = (v - mu_s[r]) * rs_s[r] * g_c + lb_c;
    Y[(size_t)(r0 + r) * 128 + c] = t * bg_c + bb_c;
  }
}

// ---------------------------------------------------------------------------
extern "C" void kernel_launch(void* const* d_in, const int* in_sizes, int n_in,
                              void* d_out, int out_size, void* d_ws, size_t ws_size,
                              hipStream_t stream) {
  const float* h_   = (const float*)d_in[0];
  const float* de   = (const float*)d_in[1];
  const float* m_   = (const float*)d_in[2];
  const float* I_   = (const float*)d_in[3];
  const float* W_Q  = (const float*)d_in[4];
  const float* b_Q  = (const float*)d_in[5];
  const float* W_K  = (const float*)d_in[6];
  const float* b_K  = (const float*)d_in[7];
  const float* W_V  = (const float*)d_in[8];
  const float* b_V  = (const float*)d_in[9];
  const float* W_pd = (const float*)d_in[10];
  const float* b_pd = (const float*)d_in[11];
  const float* W_pm = (const float*)d_in[12];
  const float* b_pm = (const float*)d_in[13];
  const float* W_i  = (const float*)d_in[14];
  const float* b_i  = (const float*)d_in[15];
  const float* W_O  = (const float*)d_in[16];
  const float* b_O  = (const float*)d_in[17];
  const float* ln1g = (const float*)d_in[18];
  const float* ln1b = (const float*)d_in[19];
  const float* bn1g = (const float*)d_in[20];
  const float* bn1b = (const float*)d_in[21];
  const float* W_f1 = (const float*)d_in[22];
  const float* b_f1 = (const float*)d_in[23];
  const float* W_f2 = (const float*)d_in[24];
  const float* b_f2 = (const float*)d_in[25];
  const float* ln2g = (const float*)d_in[26];
  const float* ln2b = (const float*)d_in[27];
  const float* bn2g = (const float*)d_in[28];
  const float* bn2b = (const float*)d_in[29];
  const int* src    = (const int*)d_in[30];
  const int* dst    = (const int*)d_in[31];

  const int N_ = in_sizes[0] / 128;   // 50000
  const int E_ = in_sizes[30];        // 800000
  const size_t ND_ = (size_t)N_ * 128;

  float* ws = (float*)d_ws;
  size_t off = 0;
  float* Qb   = ws + off; off += ND_;
  float* KVb  = ws + off; off += (size_t)N_ * 256;   // K||V interleaved
  float* wV   = ws + off; off += ND_;
  float* zb   = ws + off; off += (size_t)N_ * 8;
  float* esum = ws + off; off += (size_t)E_ * 8;
  float* Tb   = ws + off; off += ND_;
  float* h2   = ws + off; off += ND_;
  float* hid  = ws + off; off += (size_t)N_ * 256;   // FFN scratch; CSR aliased here
  float* wpd  = ws + off; off += 1024;
  float* wpm  = ws + off; off += 1024;
  float* bs   = ws + off; off += 8;
  (void)ws_size; (void)n_in; (void)out_size;

  // CSR arrays aliased into hid (dead until FFN stage)
  int*  rs     = (int*)hid;                  // N+1 (padded to N+2)
  int*  cursor = rs + (N_ + 2);              // N (padded to N+2)
  int2* eidx   = (int2*)(cursor + (N_ + 2)); // E entries (src, eid)

  float* out = (float*)d_out;
  const int nrb = (N_ + 7) / 8;
  const int nrb64 = (N_ + 63) / 64;

  // 1. weight head-sums
  k_wsum<<<9, 256, 0, stream>>>(W_pd, b_pd, W_pm, b_pm, wpd, wpm, bs);

  // 2. fused Q,KV projection (reads h once)
  k_qkv<<<nrb, 128, 0, stream>>>(h_, W_Q, b_Q, W_K, b_K, W_V, b_V, Qb, KVb, N_);

  // 3. edge bias scores (memory-bound on de + m; ~93% of stream floor)
  k_esum2<<<(E_ + 31) / 32, 256, 0, stream>>>(de, m_, wpd, wpm, bs, esum, E_);

  // 4. CSR build: counts -> scan -> scatter
  hipMemsetAsync(cursor, 0, (size_t)N_ * sizeof(int), stream);
  k_hist<<<1024, 256, 0, stream>>>(dst, cursor, E_);
  k_scan<<<1, 1024, 0, stream>>>(cursor, rs, cursor, N_);
  k_scatter<<<1024, 256, 0, stream>>>(src, dst, cursor, eidx, E_);

  // 5. gather-side attention (head-per-lane, 16 edges in flight)
  k_node_attn<<<(N_ + 3) / 4, 256, 0, stream>>>(Qb, KVb, esum, rs, eidx, wV, zb, N_);

  // 6. attn normalize + I @ W_i
  k_attn_combine<<<nrb, 128, 0, stream>>>(I_, W_i, b_i, wV, zb, Tb, N_);

  // 7. W_O + residual(h) + LN1 + BN1 -> h2
  k_gemm_ln<128><<<nrb, 128, 0, stream>>>(Tb, W_O, b_O, h_, ln1g, ln1b, bn1g, bn1b, h2, N_);

  // 8. FFN1 (ReLU), register-tiled — overwrites CSR scratch (dead by now)
  k_gemm4<128, 256, true><<<dim3(nrb64, 4), 256, 0, stream>>>(h2, W_f1, b_f1, hid, N_);

  // 9. FFN2 + residual(h2) + LN2 + BN2 -> out
  k_gemm_ln<256><<<nrb, 128, 0, stream>>>(hid, W_f2, b_f2, h2, ln2g, ln2b, bn2g, bn2b, out, N_);
}

// Round 7
// 856.411 us; speedup vs baseline: 1.2842x; 1.0066x over previous
//
#include <hip/hip_runtime.h>

// Problem constants
#define ND 128      // model dim D
#define NH 8        // heads
#define DHD 16      // head dim

// ---------------------------------------------------------------------------
// Tiny kernel: per-head column sums of W_pd / W_pm and bias sums.
// wpd/wpm layout: [k][h] -> k*8+h
// ---------------------------------------------------------------------------
__global__ void k_wsum(const float* __restrict__ Wpd, const float* __restrict__ bpd,
                       const float* __restrict__ Wpm, const float* __restrict__ bpm,
                       float* __restrict__ wpd, float* __restrict__ wpm,
                       float* __restrict__ bs) {
  int t = blockIdx.x * blockDim.x + threadIdx.x;
  if (t < 1024) {
    int k = t >> 3, h = t & 7;
    float s = 0.f;
#pragma unroll
    for (int d = 0; d < 16; ++d) s += Wpd[k * 128 + h * 16 + d];
    wpd[t] = s;
  } else if (t < 2048) {
    int u = t - 1024, k = u >> 3, h = u & 7;
    float s = 0.f;
#pragma unroll
    for (int d = 0; d < 16; ++d) s += Wpm[k * 128 + h * 16 + d];
    wpm[u] = s;
  } else if (t < 2056) {
    int h = t - 2048;
    float s = 0.f;
#pragma unroll
    for (int d = 0; d < 16; ++d) s += bpd[h * 16 + d] + bpm[h * 16 + d];
    bs[h] = s;
  }
}

// ---------------------------------------------------------------------------
// QKV projection, register-tiled 4x4. Tile 64 rows x 64 cols; grid.y in 0..5:
// mat = y>>1 (0=Q,1=K,2=V), col-half = (y&1)*64. Epilogue maps K/V into the
// interleaved KV[node][256] layout (K || V).
// ---------------------------------------------------------------------------
__global__ __launch_bounds__(256) void k_qkv4(const float* __restrict__ X,
                                              const float* __restrict__ WQ, const float* __restrict__ bQ,
                                              const float* __restrict__ WK, const float* __restrict__ bK,
                                              const float* __restrict__ WV, const float* __restrict__ bV,
                                              float* __restrict__ Q, float* __restrict__ KV,
                                              int n) {
  __shared__ float xs[64][132];
  const int t = threadIdx.x;
  const int tx = t & 15, ty = t >> 4;
  const int r0 = blockIdx.x * 64;
  const int mat = blockIdx.y >> 1;
  const int c0 = (blockIdx.y & 1) * 64;
  const float* __restrict__ W = (mat == 0) ? WQ : (mat == 1) ? WK : WV;
  const float* __restrict__ B = (mat == 0) ? bQ : (mat == 1) ? bK : bV;
  for (int i = t; i < 64 * 32; i += 256) {
    const int row = i >> 5, c4 = (i & 31) << 2;
    float4 v = make_float4(0.f, 0.f, 0.f, 0.f);
    if (r0 + row < n) v = *(const float4*)(X + (size_t)(r0 + row) * 128 + c4);
    *(float4*)&xs[row][c4] = v;
  }
  __syncthreads();
  float4 acc[4];
#pragma unroll
  for (int i = 0; i < 4; ++i) acc[i] = make_float4(0.f, 0.f, 0.f, 0.f);
  const int ty4 = ty << 2;
#pragma unroll 4
  for (int k = 0; k < 128; ++k) {
    const float4 wv = *(const float4*)(W + (size_t)k * 128 + c0 + (tx << 2));
    const float x0 = xs[ty4 + 0][k];
    const float x1 = xs[ty4 + 1][k];
    const float x2 = xs[ty4 + 2][k];
    const float x3 = xs[ty4 + 3][k];
    acc[0].x += x0 * wv.x; acc[0].y += x0 * wv.y; acc[0].z += x0 * wv.z; acc[0].w += x0 * wv.w;
    acc[1].x += x1 * wv.x; acc[1].y += x1 * wv.y; acc[1].z += x1 * wv.z; acc[1].w += x1 * wv.w;
    acc[2].x += x2 * wv.x; acc[2].y += x2 * wv.y; acc[2].z += x2 * wv.z; acc[2].w += x2 * wv.w;
    acc[3].x += x3 * wv.x; acc[3].y += x3 * wv.y; acc[3].z += x3 * wv.z; acc[3].w += x3 * wv.w;
  }
  const float4 bv = *(const float4*)(B + c0 + (tx << 2));
  float* __restrict__ Yp = (mat == 0) ? Q : KV;
  const int strideY = (mat == 0) ? 128 : 256;
  const int coff = ((mat == 2) ? 128 : 0) + c0 + (tx << 2);
#pragma unroll
  for (int i = 0; i < 4; ++i) {
    const int row = r0 + ty4 + i;
    if (row < n) {
      float4 o;
      o.x = acc[i].x + bv.x; o.y = acc[i].y + bv.y;
      o.z = acc[i].z + bv.z; o.w = acc[i].w + bv.w;
      *(float4*)(Yp + (size_t)row * strideY + coff) = o;
    }
  }
}

// ---------------------------------------------------------------------------
// Edge bias-score kernel: LDS-tiled skinny GEMM (~93% of stream floor).
// Tail: fused dst-histogram (saves a separate k_hist pass).
// ---------------------------------------------------------------------------
__global__ __launch_bounds__(256) void k_esum2(const float* __restrict__ de,
                                               const float* __restrict__ m,
                                               const float* __restrict__ wpd,
                                               const float* __restrict__ wpm,
                                               const float* __restrict__ bs,
                                               const int* __restrict__ dst,
                                               int* __restrict__ counts,
                                               float* __restrict__ esum, int E_) {
  __shared__ float sde[32 * 129];
  __shared__ float smm[32 * 129];
  __shared__ float swd[128 * 8];
  __shared__ float swm[128 * 8];
  __shared__ float part[8][32][8];
  const int t = threadIdx.x;
  for (int i = t; i < 1024; i += 256) { swd[i] = wpd[i]; swm[i] = wpm[i]; }
  const int e0 = blockIdx.x * 32;
  const int nr = min(32, E_ - e0);
  if (nr == 32) {
#pragma unroll
    for (int j = 0; j < 4; ++j) {
      const int f = t + j * 256;
      const int r = f >> 5, c = (f & 31) << 2;
      const float4 v = *(const float4*)(de + (size_t)(e0 + r) * 128 + c);
      const float4 w = *(const float4*)(m + (size_t)(e0 + r) * 128 + c);
      float* pd = &sde[r * 129 + c];
      pd[0] = v.x; pd[1] = v.y; pd[2] = v.z; pd[3] = v.w;
      float* pm2 = &smm[r * 129 + c];
      pm2[0] = w.x; pm2[1] = w.y; pm2[2] = w.z; pm2[3] = w.w;
    }
  } else {
#pragma unroll
    for (int j = 0; j < 4; ++j) {
      const int f = t + j * 256;
      const int r = f >> 5, c = (f & 31) << 2;
      float4 v = make_float4(0.f, 0.f, 0.f, 0.f), w = v;
      if (r < nr) {
        v = *(const float4*)(de + (size_t)(e0 + r) * 128 + c);
        w = *(const float4*)(m + (size_t)(e0 + r) * 128 + c);
      }
      float* pd = &sde[r * 129 + c];
      pd[0] = v.x; pd[1] = v.y; pd[2] = v.z; pd[3] = v.w;
      float* pm2 = &smm[r * 129 + c];
      pm2[0] = w.x; pm2[1] = w.y; pm2[2] = w.z; pm2[3] = w.w;
    }
  }
  __syncthreads();
  const int el = t & 31, kc = t >> 5;
  float acc[8];
#pragma unroll
  for (int h = 0; h < 8; ++h) acc[h] = 0.f;
  const int kbase = kc << 4;
#pragma unroll
  for (int j = 0; j < 16; ++j) {
    const int k = kbase + j;
    const float d = sde[el * 129 + k];
    const float mm = smm[el * 129 + k];
    const float4 w0 = *(const float4*)&swd[k * 8];
    const float4 w1 = *(const float4*)&swd[k * 8 + 4];
    const float4 x0 = *(const float4*)&swm[k * 8];
    const float4 x1 = *(const float4*)&swm[k * 8 + 4];
    acc[0] += d * w0.x + mm * x0.x;
    acc[1] += d * w0.y + mm * x0.y;
    acc[2] += d * w0.z + mm * x0.z;
    acc[3] += d * w0.w + mm * x0.w;
    acc[4] += d * w1.x + mm * x1.x;
    acc[5] += d * w1.y + mm * x1.y;
    acc[6] += d * w1.z + mm * x1.z;
    acc[7] += d * w1.w + mm * x1.w;
  }
  *(float4*)&part[kc][el][0] = make_float4(acc[0], acc[1], acc[2], acc[3]);
  *(float4*)&part[kc][el][4] = make_float4(acc[4], acc[5], acc[6], acc[7]);
  __syncthreads();
  const int el2 = t >> 3, h = t & 7;
  float s = bs[h];
#pragma unroll
  for (int kk = 0; kk < 8; ++kk) s += part[kk][el2][h];
  if (el2 < nr) esum[(size_t)(e0 + el2) * 8 + h] = s;
  // fused histogram of dst for this block's edges
  if (t < nr) atomicAdd(&counts[dst[e0 + t]], 1);
}

// ---------------------------------------------------------------------------
// CSR build: scan + scatter (hist fused into esum2)
// ---------------------------------------------------------------------------
__global__ __launch_bounds__(1024) void k_scan(const int* __restrict__ counts,
                                               int* __restrict__ rs,
                                               int* __restrict__ cursor, int N_) {
  __shared__ int ls[1024];
  const int t = threadIdx.x;
  const int CH = (N_ + 1023) >> 10;
  const int b0 = t * CH, b1 = min(N_, b0 + CH);
  int s = 0;
  for (int i = b0; i < b1; ++i) s += counts[i];
  ls[t] = s;
  __syncthreads();
  for (int off = 1; off < 1024; off <<= 1) {
    int v = (t >= off) ? ls[t - off] : 0;
    __syncthreads();
    ls[t] += v;
    __syncthreads();
  }
  int run = ls[t] - s;
  for (int i = b0; i < b1; ++i) {
    rs[i] = run;
    cursor[i] = run;
    run += counts[i];
  }
  if (t == 1023) rs[N_] = ls[1023];
}

__global__ __launch_bounds__(256) void k_scatter(const int* __restrict__ src,
                                                 const int* __restrict__ dst,
                                                 int* __restrict__ cursor,
                                                 int2* __restrict__ eidx, int E_) {
  const int i = blockIdx.x * blockDim.x + threadIdx.x;
  const int n = gridDim.x * blockDim.x;
  for (int e = i; e < E_; e += n) {
    int d = dst[e];
    int p = atomicAdd(&cursor[d], 1);
    eidx[p] = make_int2(src[e], e);
  }
}

// ---------------------------------------------------------------------------
// Gather-side attention: one wave per dst node, head-per-lane layout,
// 16 edges in flight (two 8-edge slots), branch-free clamped loads.
// ---------------------------------------------------------------------------
__global__ __launch_bounds__(256) void k_node_attn(const float* __restrict__ Q,
                                                   const float* __restrict__ KV,
                                                   const float* __restrict__ esum,
                                                   const int* __restrict__ rs,
                                                   const int2* __restrict__ eidx,
                                                   float* __restrict__ wV,
                                                   float* __restrict__ z, int n) {
  const int node = (blockIdx.x * blockDim.x + threadIdx.x) >> 6;
  if (node >= n) return;
  const int lane = threadIdx.x & 63;
  const int g = lane >> 3;   // edge slot
  const int l = lane & 7;    // head
  const int d0 = l << 4;     // this head's dim base
  const float* qp = Q + (size_t)node * 128 + d0;
  const float4 q0 = *(const float4*)(qp);
  const float4 q1 = *(const float4*)(qp + 4);
  const float4 q2 = *(const float4*)(qp + 8);
  const float4 q3 = *(const float4*)(qp + 12);
  float4 a0 = make_float4(0.f, 0.f, 0.f, 0.f);
  float4 a1 = a0, a2 = a0, a3 = a0;
  float zacc = 0.f;
  const int start = rs[node], end = rs[node + 1];
  for (int base = start; base < end; base += 16) {
    const bool p0 = base + g < end;
    const bool p1 = base + 8 + g < end;
    const int i0 = min(base + g, end - 1);
    const int i1 = min(base + 8 + g, end - 1);
    const int2 m0 = eidx[i0];
    const int2 m1 = eidx[i1];
    const float* kp0 = KV + (size_t)m0.x * 256 + d0;
    const float* kp1 = KV + (size_t)m1.x * 256 + d0;
    const float es0 = esum[(size_t)m0.y * 8 + l];
    const float es1 = esum[(size_t)m1.y * 8 + l];
    float4 k0, k1, k2, k3;
    // edge slot 0
    k0 = *(const float4*)(kp0);
    k1 = *(const float4*)(kp0 + 4);
    k2 = *(const float4*)(kp0 + 8);
    k3 = *(const float4*)(kp0 + 12);
    float qkA = q0.x * k0.x + q0.y * k0.y + q0.z * k0.z + q0.w * k0.w
              + q1.x * k1.x + q1.y * k1.y + q1.z * k1.z + q1.w * k1.w
              + q2.x * k2.x + q2.y * k2.y + q2.z * k2.z + q2.w * k2.w
              + q3.x * k3.x + q3.y * k3.y + q3.z * k3.z + q3.w * k3.w;
    // edge slot 1
    k0 = *(const float4*)(kp1);
    k1 = *(const float4*)(kp1 + 4);
    k2 = *(const float4*)(kp1 + 8);
    k3 = *(const float4*)(kp1 + 12);
    float qkB = q0.x * k0.x + q0.y * k0.y + q0.z * k0.z + q0.w * k0.w
              + q1.x * k1.x + q1.y * k1.y + q1.z * k1.z + q1.w * k1.w
              + q2.x * k2.x + q2.y * k2.y + q2.z * k2.z + q2.w * k2.w
              + q3.x * k3.x + q3.y * k3.y + q3.z * k3.z + q3.w * k3.w;
    float s0 = __expf(fminf(5.f, fmaxf(-5.f, 4.f * qkA + es0)));
    float s1 = __expf(fminf(5.f, fmaxf(-5.f, 4.f * qkB + es1)));
    s0 = p0 ? s0 : 0.f;
    s1 = p1 ? s1 : 0.f;
    {
      const float* vp = kp0 + 128;
      const float4 v0 = *(const float4*)(vp);
      const float4 v1 = *(const float4*)(vp + 4);
      const float4 v2 = *(const float4*)(vp + 8);
      const float4 v3 = *(const float4*)(vp + 12);
      a0.x += v0.x * s0; a0.y += v0.y * s0; a0.z += v0.z * s0; a0.w += v0.w * s0;
      a1.x += v1.x * s0; a1.y += v1.y * s0; a1.z += v1.z * s0; a1.w += v1.w * s0;
      a2.x += v2.x * s0; a2.y += v2.y * s0; a2.z += v2.z * s0; a2.w += v2.w * s0;
      a3.x += v3.x * s0; a3.y += v3.y * s0; a3.z += v3.z * s0; a3.w += v3.w * s0;
    }
    {
      const float* vp = kp1 + 128;
      const float4 v0 = *(const float4*)(vp);
      const float4 v1 = *(const float4*)(vp + 4);
      const float4 v2 = *(const float4*)(vp + 8);
      const float4 v3 = *(const float4*)(vp + 12);
      a0.x += v0.x * s1; a0.y += v0.y * s1; a0.z += v0.z * s1; a0.w += v0.w * s1;
      a1.x += v1.x * s1; a1.y += v1.y * s1; a1.z += v1.z * s1; a1.w += v1.w * s1;
      a2.x += v2.x * s1; a2.y += v2.y * s1; a2.z += v2.z * s1; a2.w += v2.w * s1;
      a3.x += v3.x * s1; a3.y += v3.y * s1; a3.z += v3.z * s1; a3.w += v3.w * s1;
    }
    zacc += s0 + s1;
  }
#pragma unroll
  for (int st = 8; st < 64; st <<= 1) {
    a0.x += __shfl_xor(a0.x, st); a0.y += __shfl_xor(a0.y, st);
    a0.z += __shfl_xor(a0.z, st); a0.w += __shfl_xor(a0.w, st);
    a1.x += __shfl_xor(a1.x, st); a1.y += __shfl_xor(a1.y, st);
    a1.z += __shfl_xor(a1.z, st); a1.w += __shfl_xor(a1.w, st);
    a2.x += __shfl_xor(a2.x, st); a2.y += __shfl_xor(a2.y, st);
    a2.z += __shfl_xor(a2.z, st); a2.w += __shfl_xor(a2.w, st);
    a3.x += __shfl_xor(a3.x, st); a3.y += __shfl_xor(a3.y, st);
    a3.z += __shfl_xor(a3.z, st); a3.w += __shfl_xor(a3.w, st);
    zacc += __shfl_xor(zacc, st);
  }
  if (g < 4) {
    float4 w = a0;
    if (g == 1) w = a1;
    if (g == 2) w = a2;
    if (g == 3) w = a3;
    *(float4*)(wV + (size_t)node * 128 + d0 + (g << 2)) = w;
  }
  if (g == 0) z[(size_t)node * 8 + l] = zacc;
}

// ---------------------------------------------------------------------------
// attn normalize + I @ W_i + b_i  -> T[n,128]
// ---------------------------------------------------------------------------
__global__ __launch_bounds__(128) void k_attn_combine(const float* __restrict__ I_,
                                                      const float* __restrict__ Wi,
                                                      const float* __restrict__ bi,
                                                      const float* __restrict__ wV,
                                                      const float* __restrict__ z,
                                                      float* __restrict__ T, int n) {
  __shared__ float xs[8][64];
  const int c = threadIdx.x;
  const int r0 = blockIdx.x * 8;
  const int nr = min(8, n - r0);
  for (int i = c; i < nr * 64; i += 128) xs[i >> 6][i & 63] = I_[r0 * 64 + i];
  __syncthreads();
  float acc[8];
#pragma unroll
  for (int r = 0; r < 8; ++r) acc[r] = 0.f;
  for (int k = 0; k < 64; ++k) {
    float w = Wi[k * 128 + c];
#pragma unroll
    for (int r = 0; r < 8; ++r) acc[r] += xs[r][k] * w;
  }
  const float b = bi[c];
  const int hh = c >> 4;
  for (int r = 0; r < nr; ++r) {
    const size_t row = r0 + r;
    const float attn = wV[row * 128 + c] / (z[row * 8 + hh] + 1e-10f);
    T[row * 128 + c] = attn + acc[r] + b;
  }
}

// ---------------------------------------------------------------------------
// 4x4 register-tiled GEMM + bias (+ReLU): 64x64 tile, 256 threads.
// ---------------------------------------------------------------------------
template <int CI, int CO, bool RELU>
__global__ __launch_bounds__(256) void k_gemm4(const float* __restrict__ X,
                                               const float* __restrict__ W,
                                               const float* __restrict__ B,
                                               float* __restrict__ Y, int n) {
  __shared__ float xs[64][CI + 4];
  const int t = threadIdx.x;
  const int tx = t & 15, ty = t >> 4;
  const int r0 = blockIdx.x * 64;
  const int c0 = blockIdx.y * 64;
  const int NV = 64 * (CI / 4);
  for (int i = t; i < NV; i += 256) {
    const int row = i / (CI / 4);
    const int c4 = (i % (CI / 4)) << 2;
    float4 v = make_float4(0.f, 0.f, 0.f, 0.f);
    if (r0 + row < n) v = *(const float4*)(X + (size_t)(r0 + row) * CI + c4);
    *(float4*)&xs[row][c4] = v;
  }
  __syncthreads();
  float4 acc[4];
#pragma unroll
  for (int i = 0; i < 4; ++i) acc[i] = make_float4(0.f, 0.f, 0.f, 0.f);
  const int ty4 = ty << 2;
#pragma unroll 4
  for (int k = 0; k < CI; ++k) {
    const float4 wv = *(const float4*)(W + (size_t)k * CO + c0 + (tx << 2));
    const float x0 = xs[ty4 + 0][k];
    const float x1 = xs[ty4 + 1][k];
    const float x2 = xs[ty4 + 2][k];
    const float x3 = xs[ty4 + 3][k];
    acc[0].x += x0 * wv.x; acc[0].y += x0 * wv.y; acc[0].z += x0 * wv.z; acc[0].w += x0 * wv.w;
    acc[1].x += x1 * wv.x; acc[1].y += x1 * wv.y; acc[1].z += x1 * wv.z; acc[1].w += x1 * wv.w;
    acc[2].x += x2 * wv.x; acc[2].y += x2 * wv.y; acc[2].z += x2 * wv.z; acc[2].w += x2 * wv.w;
    acc[3].x += x3 * wv.x; acc[3].y += x3 * wv.y; acc[3].z += x3 * wv.z; acc[3].w += x3 * wv.w;
  }
  const float4 bv = *(const float4*)(B + c0 + (tx << 2));
#pragma unroll
  for (int i = 0; i < 4; ++i) {
    const int row = r0 + ty4 + i;
    if (row < n) {
      float4 o;
      o.x = acc[i].x + bv.x; o.y = acc[i].y + bv.y;
      o.z = acc[i].z + bv.z; o.w = acc[i].w + bv.w;
      if (RELU) {
        o.x = fmaxf(o.x, 0.f); o.y = fmaxf(o.y, 0.f);
        o.z = fmaxf(o.z, 0.f); o.w = fmaxf(o.w, 0.f);
      }
      *(float4*)(Y + (size_t)row * CO + c0 + (tx << 2)) = o;
    }
  }
}

// ---------------------------------------------------------------------------
// Register-tiled GEMM (CI->128) + bias + residual + LN + eval-BN, fused.
// 32 rows x 128 cols per 256-thread block; thread = 4 rows x 4 cols.
// Row stats via 5-stage shfl_xor across the 32-lane tx group.
// ---------------------------------------------------------------------------
template <int CI>
__global__ __launch_bounds__(256) void k_gemm4ln(const float* __restrict__ X,
                                                 const float* __restrict__ W,
                                                 const float* __restrict__ B,
                                                 const float* __restrict__ RES,
                                                 const float* __restrict__ lng,
                                                 const float* __restrict__ lnb,
                                                 const float* __restrict__ bng,
                                                 const float* __restrict__ bnb,
                                                 float* __restrict__ Y, int n) {
  __shared__ float xs[32][CI + 4];
  const int t = threadIdx.x;
  const int tx = t & 31, ty = t >> 5;
  const int r0 = blockIdx.x * 32;
  const int cb = tx << 2;
  for (int i = t; i < 32 * (CI / 4); i += 256) {
    const int row = i / (CI / 4);
    const int c4 = (i % (CI / 4)) << 2;
    float4 v = make_float4(0.f, 0.f, 0.f, 0.f);
    if (r0 + row < n) v = *(const float4*)(X + (size_t)(r0 + row) * CI + c4);
    *(float4*)&xs[row][c4] = v;
  }
  __syncthreads();
  float4 acc[4];
#pragma unroll
  for (int i = 0; i < 4; ++i) acc[i] = make_float4(0.f, 0.f, 0.f, 0.f);
  const int ty4 = ty << 2;
#pragma unroll 4
  for (int k = 0; k < CI; ++k) {
    const float4 wv = *(const float4*)(W + (size_t)k * 128 + cb);
    const float x0 = xs[ty4 + 0][k];
    const float x1 = xs[ty4 + 1][k];
    const float x2 = xs[ty4 + 2][k];
    const float x3 = xs[ty4 + 3][k];
    acc[0].x += x0 * wv.x; acc[0].y += x0 * wv.y; acc[0].z += x0 * wv.z; acc[0].w += x0 * wv.w;
    acc[1].x += x1 * wv.x; acc[1].y += x1 * wv.y; acc[1].z += x1 * wv.z; acc[1].w += x1 * wv.w;
    acc[2].x += x2 * wv.x; acc[2].y += x2 * wv.y; acc[2].z += x2 * wv.z; acc[2].w += x2 * wv.w;
    acc[3].x += x3 * wv.x; acc[3].y += x3 * wv.y; acc[3].z += x3 * wv.z; acc[3].w += x3 * wv.w;
  }
  const float4 bv  = *(const float4*)(B + cb);
  const float4 g4  = *(const float4*)(lng + cb);
  const float4 lb4 = *(const float4*)(lnb + cb);
  const float bnscale = rsqrtf(1.f + 1e-5f);
  float4 bg4 = *(const float4*)(bng + cb);
  bg4.x *= bnscale; bg4.y *= bnscale; bg4.z *= bnscale; bg4.w *= bnscale;
  const float4 bb4 = *(const float4*)(bnb + cb);
#pragma unroll
  for (int i = 0; i < 4; ++i) {
    const int row = r0 + ty4 + i;
    float4 v = acc[i];
    v.x += bv.x; v.y += bv.y; v.z += bv.z; v.w += bv.w;
    if (row < n) {
      const float4 rr = *(const float4*)(RES + (size_t)row * 128 + cb);
      v.x += rr.x; v.y += rr.y; v.z += rr.z; v.w += rr.w;
    }
    float s1 = v.x + v.y + v.z + v.w;
    float s2 = v.x * v.x + v.y * v.y + v.z * v.z + v.w * v.w;
#pragma unroll
    for (int st = 1; st < 32; st <<= 1) {
      s1 += __shfl_xor(s1, st);
      s2 += __shfl_xor(s2, st);
    }
    const float mu = s1 * (1.f / 128.f);
    const float var = s2 * (1.f / 128.f) - mu * mu;
    const float rsg = rsqrtf(var + 1e-5f);
    if (row < n) {
      float4 o;
      o.x = ((v.x - mu) * rsg * g4.x + lb4.x) * bg4.x + bb4.x;
      o.y = ((v.y - mu) * rsg * g4.y + lb4.y) * bg4.y + bb4.y;
      o.z = ((v.z - mu) * rsg * g4.z + lb4.z) * bg4.z + bb4.z;
      o.w = ((v.w - mu) * rsg * g4.w + lb4.w) * bg4.w + bb4.w;
      *(float4*)(Y + (size_t)row * 128 + cb) = o;
    }
  }
}

// ---------------------------------------------------------------------------
extern "C" void kernel_launch(void* const* d_in, const int* in_sizes, int n_in,
                              void* d_out, int out_size, void* d_ws, size_t ws_size,
                              hipStream_t stream) {
  const float* h_   = (const float*)d_in[0];
  const float* de   = (const float*)d_in[1];
  const float* m_   = (const float*)d_in[2];
  const float* I_   = (const float*)d_in[3];
  const float* W_Q  = (const float*)d_in[4];
  const float* b_Q  = (const float*)d_in[5];
  const float* W_K  = (const float*)d_in[6];
  const float* b_K  = (const float*)d_in[7];
  const float* W_V  = (const float*)d_in[8];
  const float* b_V  = (const float*)d_in[9];
  const float* W_pd = (const float*)d_in[10];
  const float* b_pd = (const float*)d_in[11];
  const float* W_pm = (const float*)d_in[12];
  const float* b_pm = (const float*)d_in[13];
  const float* W_i  = (const float*)d_in[14];
  const float* b_i  = (const float*)d_in[15];
  const float* W_O  = (const float*)d_in[16];
  const float* b_O  = (const float*)d_in[17];
  const float* ln1g = (const float*)d_in[18];
  const float* ln1b = (const float*)d_in[19];
  const float* bn1g = (const float*)d_in[20];
  const float* bn1b = (const float*)d_in[21];
  const float* W_f1 = (const float*)d_in[22];
  const float* b_f1 = (const float*)d_in[23];
  const float* W_f2 = (const float*)d_in[24];
  const float* b_f2 = (const float*)d_in[25];
  const float* ln2g = (const float*)d_in[26];
  const float* ln2b = (const float*)d_in[27];
  const float* bn2g = (const float*)d_in[28];
  const float* bn2b = (const float*)d_in[29];
  const int* src    = (const int*)d_in[30];
  const int* dst    = (const int*)d_in[31];

  const int N_ = in_sizes[0] / 128;   // 50000
  const int E_ = in_sizes[30];        // 800000
  const size_t ND_ = (size_t)N_ * 128;

  float* ws = (float*)d_ws;
  size_t off = 0;
  float* Qb   = ws + off; off += ND_;
  float* KVb  = ws + off; off += (size_t)N_ * 256;   // K||V interleaved
  float* wV   = ws + off; off += ND_;
  float* zb   = ws + off; off += (size_t)N_ * 8;
  float* esum = ws + off; off += (size_t)E_ * 8;
  float* Tb   = ws + off; off += ND_;
  float* h2   = ws + off; off += ND_;
  float* hid  = ws + off; off += (size_t)N_ * 256;   // FFN scratch; CSR aliased here
  float* wpd  = ws + off; off += 1024;
  float* wpm  = ws + off; off += 1024;
  float* bs   = ws + off; off += 8;
  (void)ws_size; (void)n_in; (void)out_size;

  // CSR arrays aliased into hid (dead until FFN stage)
  int*  rs     = (int*)hid;                  // N+1 (padded to N+2)
  int*  cursor = rs + (N_ + 2);              // N (padded to N+2)
  int2* eidx   = (int2*)(cursor + (N_ + 2)); // E entries (src, eid)

  float* out = (float*)d_out;
  const int nrb = (N_ + 7) / 8;
  const int nrb32 = (N_ + 31) / 32;
  const int nrb64 = (N_ + 63) / 64;

  // 1. weight head-sums; zero counts for fused histogram
  k_wsum<<<9, 256, 0, stream>>>(W_pd, b_pd, W_pm, b_pm, wpd, wpm, bs);
  hipMemsetAsync(cursor, 0, (size_t)N_ * sizeof(int), stream);

  // 2. Q,KV projection (register-tiled)
  k_qkv4<<<dim3(nrb64, 6), 256, 0, stream>>>(h_, W_Q, b_Q, W_K, b_K, W_V, b_V, Qb, KVb, N_);

  // 3. edge bias scores (memory-bound on de + m) + fused dst histogram
  k_esum2<<<(E_ + 31) / 32, 256, 0, stream>>>(de, m_, wpd, wpm, bs, dst, cursor, esum, E_);

  // 4. CSR: scan -> scatter
  k_scan<<<1, 1024, 0, stream>>>(cursor, rs, cursor, N_);
  k_scatter<<<1024, 256, 0, stream>>>(src, dst, cursor, eidx, E_);

  // 5. gather-side attention (head-per-lane, 16 edges in flight)
  k_node_attn<<<(N_ + 3) / 4, 256, 0, stream>>>(Qb, KVb, esum, rs, eidx, wV, zb, N_);

  // 6. attn normalize + I @ W_i
  k_attn_combine<<<nrb, 128, 0, stream>>>(I_, W_i, b_i, wV, zb, Tb, N_);

  // 7. W_O + residual(h) + LN1 + BN1 -> h2 (register-tiled, fused)
  k_gemm4ln<128><<<nrb32, 256, 0, stream>>>(Tb, W_O, b_O, h_, ln1g, ln1b, bn1g, bn1b, h2, N_);

  // 8. FFN1 (ReLU), register-tiled — overwrites CSR scratch (dead by now)
  k_gemm4<128, 256, true><<<dim3(nrb64, 4), 256, 0, stream>>>(h2, W_f1, b_f1, hid, N_);

  // 9. FFN2 + residual(h2) + LN2 + BN2 -> out (register-tiled, fused)
  k_gemm4ln<256><<<nrb32, 256, 0, stream>>>(hid, W_f2, b_f2, h2, ln2g, ln2b, bn2g, bn2b, out, N_);
}